// Round 4
// baseline (116.027 us; speedup 1.0000x reference)
//
#include <hip/hip_runtime.h>
#include <hip/hip_bf16.h>
#include <math.h>

#define N 4096
#define NGRP 16   // level-1 reduction groups

__inline__ __device__ float waveReduceSum(float v) {
    #pragma unroll
    for (int o = 32; o > 0; o >>= 1) v += __shfl_down(v, o);
    return v;
}

#define LD4(p, o) (*reinterpret_cast<const float4*>((p) + (o)))

// Combined kernel.
// Blocks [0, nWh): wh partials. Block (xt, cy) covers cols [xt*2048, xt*2048+2048)
//   and rows [cy*CHUNK, cy*CHUNK+CHUNK). Each thread owns 2 float4 slots per row,
//   register double-buffered: prefetch row r+1 (6 loads in flight) while FMAing row r.
// Blocks [nWh, nWh+N): wx[j] = relu(dot(x, w_in[j,:])), one block per row.
template<int CHUNK>
__global__ __launch_bounds__(256) void k_combo1(const float* __restrict__ x,
                                                const float* __restrict__ w_in,
                                                const float* __restrict__ hid,
                                                const float* __restrict__ w,
                                                const float* __restrict__ alpha,
                                                const float* __restrict__ hebb,
                                                float* __restrict__ part,
                                                float* __restrict__ wx_out,
                                                int nWh) {
    if ((int)blockIdx.x < nWh) {
        int bid = blockIdx.x;
        int xt  = bid & 1;                  // 2 column tiles of 2048
        int cy  = bid >> 1;
        int i0  = cy * CHUNK;
        int j   = xt * 2048 + threadIdx.x * 4;   // slot A; slot B at j+1024
        size_t base = (size_t)i0 * N + j;

        float hv[CHUNK];
        #pragma unroll
        for (int r = 0; r < CHUNK; ++r) hv[r] = hid[i0 + r];

        const float* wp = w + base;
        const float* ap = alpha + base;
        const float* hp = hebb + base;

        float4 cwA = LD4(wp, 0),    caA = LD4(ap, 0),    chA = LD4(hp, 0);
        float4 cwB = LD4(wp, 1024), caB = LD4(ap, 1024), chB = LD4(hp, 1024);
        float4 accA = make_float4(0.f, 0.f, 0.f, 0.f);
        float4 accB = make_float4(0.f, 0.f, 0.f, 0.f);

        #pragma unroll
        for (int r = 0; r < CHUNK; ++r) {
            float4 nwA, naA, nhA, nwB, naB, nhB;
            if (r + 1 < CHUNK) {
                size_t o = (size_t)(r + 1) * N;
                nwA = LD4(wp, o);        naA = LD4(ap, o);        nhA = LD4(hp, o);
                nwB = LD4(wp, o + 1024); naB = LD4(ap, o + 1024); nhB = LD4(hp, o + 1024);
            }
            float h = hv[r];
            accA.x = fmaf(h, fmaf(caA.x, chA.x, cwA.x), accA.x);
            accA.y = fmaf(h, fmaf(caA.y, chA.y, cwA.y), accA.y);
            accA.z = fmaf(h, fmaf(caA.z, chA.z, cwA.z), accA.z);
            accA.w = fmaf(h, fmaf(caA.w, chA.w, cwA.w), accA.w);
            accB.x = fmaf(h, fmaf(caB.x, chB.x, cwB.x), accB.x);
            accB.y = fmaf(h, fmaf(caB.y, chB.y, cwB.y), accB.y);
            accB.z = fmaf(h, fmaf(caB.z, chB.z, cwB.z), accB.z);
            accB.w = fmaf(h, fmaf(caB.w, chB.w, cwB.w), accB.w);
            cwA = nwA; caA = naA; chA = nhA;
            cwB = nwB; caB = naB; chB = nhB;
        }
        float* pp = part + (size_t)cy * N + j;
        *reinterpret_cast<float4*>(pp)        = accA;
        *reinterpret_cast<float4*>(pp + 1024) = accB;
    } else {
        int jr = blockIdx.x - nWh;
        const float4* row = reinterpret_cast<const float4*>(w_in + (size_t)jr * N);
        const float4* xv  = reinterpret_cast<const float4*>(x);
        float sum = 0.f;
        #pragma unroll
        for (int k = threadIdx.x; k < N / 4; k += 256) {
            float4 a = row[k], c = xv[k];
            sum += a.x * c.x + a.y * c.y + a.z * c.z + a.w * c.w;
        }
        sum = waveReduceSum(sum);
        __shared__ float wsum[4];
        int wid = threadIdx.x >> 6, lane = threadIdx.x & 63;
        if (lane == 0) wsum[wid] = sum;
        __syncthreads();
        if (threadIdx.x == 0)
            wx_out[jr] = fmaxf(wsum[0] + wsum[1] + wsum[2] + wsum[3], 0.f);
    }
}

// eta partials, same register-pipelined pattern, single matrix
template<int CHUNK>
__global__ __launch_bounds__(256) void k_eta_part(const float* __restrict__ wh,
                                                  const float* __restrict__ pe,
                                                  float* __restrict__ part) {
    int bid = blockIdx.x;
    int xt  = bid & 1;
    int cy  = bid >> 1;
    int i0  = cy * CHUNK;
    int j   = xt * 2048 + threadIdx.x * 4;
    size_t base = (size_t)i0 * N + j;

    float hv[CHUNK];
    #pragma unroll
    for (int r = 0; r < CHUNK; ++r) hv[r] = wh[i0 + r];

    const float* pp = pe + base;
    float4 cA = LD4(pp, 0);
    float4 cB = LD4(pp, 1024);
    float4 accA = make_float4(0.f, 0.f, 0.f, 0.f);
    float4 accB = make_float4(0.f, 0.f, 0.f, 0.f);

    #pragma unroll
    for (int r = 0; r < CHUNK; ++r) {
        float4 nA, nB;
        if (r + 1 < CHUNK) {
            size_t o = (size_t)(r + 1) * N;
            nA = LD4(pp, o);
            nB = LD4(pp, o + 1024);
        }
        float h = hv[r];
        accA.x = fmaf(h, cA.x, accA.x);
        accA.y = fmaf(h, cA.y, accA.y);
        accA.z = fmaf(h, cA.z, accA.z);
        accA.w = fmaf(h, cA.w, accA.w);
        accB.x = fmaf(h, cB.x, accB.x);
        accB.y = fmaf(h, cB.y, accB.y);
        accB.z = fmaf(h, cB.z, accB.z);
        accB.w = fmaf(h, cB.w, accB.w);
        cA = nA; cB = nB;
    }
    float* op = part + (size_t)cy * N + j;
    *reinterpret_cast<float4*>(op)        = accA;
    *reinterpret_cast<float4*>(op + 1024) = accB;
}

// level-1 reduction: part2[g*N + j] = sum_{c in group g} part[c*N + j]
__global__ __launch_bounds__(256) void k_red(const float* __restrict__ part,
                                             float* __restrict__ part2,
                                             int cpg) {
    int g  = blockIdx.y;
    int j0 = (blockIdx.x * 256 + threadIdx.x) * 4;
    const float4* p4 = reinterpret_cast<const float4*>(part);
    float4 s = make_float4(0.f, 0.f, 0.f, 0.f);
    #pragma unroll 4
    for (int c = 0; c < cpg; ++c) {
        float4 v = p4[((size_t)(g * cpg + c) * N + j0) >> 2];
        s.x += v.x; s.y += v.y; s.z += v.z; s.w += v.w;
    }
    *reinterpret_cast<float4*>(part2 + (size_t)g * N + j0) = s;
}

// finalize wh from part2 (+b), s = wx + wh, LayerNorm, relu -> wy; also writes wh
__global__ __launch_bounds__(1024) void k_ln(const float* __restrict__ part2,
                                             const float* __restrict__ b,
                                             const float* __restrict__ wx,
                                             const float* __restrict__ gamma,
                                             const float* __restrict__ beta,
                                             float* __restrict__ wh_out,
                                             float* __restrict__ wy_out) {
    __shared__ float red[16];
    __shared__ float bc[2];
    int tid = threadIdx.x;
    int wid = tid >> 6, lane = tid & 63;
    float sv[4];
    float lsum = 0.f;
    #pragma unroll
    for (int q = 0; q < 4; ++q) {
        int j = q * 1024 + tid;
        float acc = b[j];
        #pragma unroll
        for (int g = 0; g < NGRP; ++g) acc += part2[(size_t)g * N + j];
        wh_out[j] = acc;
        float s = acc + wx[j];
        sv[q] = s;
        lsum += s;
    }
    float wv = waveReduceSum(lsum);
    if (lane == 0) red[wid] = wv;
    __syncthreads();
    if (tid < 64) {
        float t = (tid < 16) ? red[tid] : 0.f;
        t = waveReduceSum(t);
        if (tid == 0) bc[0] = t * (1.f / N);
    }
    __syncthreads();
    float mean = bc[0];
    __syncthreads();
    float lsq = 0.f;
    #pragma unroll
    for (int q = 0; q < 4; ++q) { float d = sv[q] - mean; lsq += d * d; }
    wv = waveReduceSum(lsq);
    if (lane == 0) red[wid] = wv;
    __syncthreads();
    if (tid < 64) {
        float t = (tid < 16) ? red[tid] : 0.f;
        t = waveReduceSum(t);
        if (tid == 0) bc[1] = t * (1.f / N);
    }
    __syncthreads();
    float rstd = rsqrtf(bc[1] + 1e-5f);
    #pragma unroll
    for (int q = 0; q < 4; ++q) {
        int j = q * 1024 + tid;
        float ln = fmaf(gamma[j] * (sv[q] - mean), rstd, beta[j]);
        wy_out[j] = fmaxf(ln, 0.f);
    }
}

// eta[j] = sigmoid(pb[j] + sum_g part2[g*N + j])
__global__ __launch_bounds__(256) void k_eta_fin(const float* __restrict__ part2,
                                                 const float* __restrict__ pb,
                                                 float* __restrict__ eta) {
    int j0 = (blockIdx.x * 256 + threadIdx.x) * 4;
    float4 s = *reinterpret_cast<const float4*>(pb + j0);
    #pragma unroll
    for (int g = 0; g < NGRP; ++g) {
        float4 v = *reinterpret_cast<const float4*>(part2 + (size_t)g * N + j0);
        s.x += v.x; s.y += v.y; s.z += v.z; s.w += v.w;
    }
    float4 r;
    r.x = 1.f / (1.f + expf(-s.x));
    r.y = 1.f / (1.f + expf(-s.y));
    r.z = 1.f / (1.f + expf(-s.z));
    r.w = 1.f / (1.f + expf(-s.w));
    *reinterpret_cast<float4*>(eta + j0) = r;
}

// hebb_new[i,j] = (1-lamda)*hebb[i,j] + eta[i]*hid[i]*wh[j]; one block per row (16KB contiguous)
__global__ __launch_bounds__(256) void k_hebb(const float* __restrict__ hebb,
                                              const float* __restrict__ eta,
                                              const float* __restrict__ hid,
                                              const float* __restrict__ wh,
                                              const float* __restrict__ lamda,
                                              float* __restrict__ out) {
    int i  = blockIdx.x;
    float decay = 1.f - lamda[0];
    float coef  = eta[i] * hid[i];
    size_t base = (size_t)i * N;
    int j0 = threadIdx.x * 16;
    #pragma unroll
    for (int q = 0; q < 4; ++q) {
        int j = j0 + q * 4;
        float4 h  = *reinterpret_cast<const float4*>(hebb + base + j);
        float4 w4 = *reinterpret_cast<const float4*>(wh + j);
        float4 r;
        r.x = fmaf(decay, h.x, coef * w4.x);
        r.y = fmaf(decay, h.y, coef * w4.y);
        r.z = fmaf(decay, h.z, coef * w4.z);
        r.w = fmaf(decay, h.w, coef * w4.w);
        *reinterpret_cast<float4*>(out + base + j) = r;
    }
}

extern "C" void kernel_launch(void* const* d_in, const int* in_sizes, int n_in,
                              void* d_out, int out_size, void* d_ws, size_t ws_size,
                              hipStream_t stream) {
    const float* x         = (const float*)d_in[0];
    const float* hid       = (const float*)d_in[1];
    const float* hebb      = (const float*)d_in[2];
    const float* w_in      = (const float*)d_in[3];
    const float* w         = (const float*)d_in[4];
    const float* alpha     = (const float*)d_in[5];
    const float* b         = (const float*)d_in[6];
    const float* lamda     = (const float*)d_in[7];
    const float* pred_eta  = (const float*)d_in[8];
    const float* pred_eta_b= (const float*)d_in[9];
    const float* ln_gamma  = (const float*)d_in[10];
    const float* ln_beta   = (const float*)d_in[11];

    float* wy       = (float*)d_out;
    float* hebb_out = (float*)d_out + N;

    const size_t needF8 = ((size_t)(N / 8) * N) + (size_t)NGRP * N + 3 * N;
    bool big = (ws_size / 4) >= needF8;

    float* ws = (float*)d_ws;
    int nchunk = big ? (N / 8) : (N / 32);
    float* part  = ws;
    float* part2 = ws + (size_t)nchunk * N;
    float* wx    = part2 + (size_t)NGRP * N;
    float* wh    = wx + N;
    float* eta   = wh + N;
    int cpg = nchunk / NGRP;

    if (big) {
        int nWh = 2 * (N / 8);   // 1024 blocks: 2 col-tiles x 512 chunks
        k_combo1<8><<<nWh + N, 256, 0, stream>>>(x, w_in, hid, w, alpha, hebb, part, wx, nWh);
        k_red    <<<dim3(4, NGRP), 256, 0, stream>>>(part, part2, cpg);
        k_ln     <<<1, 1024, 0, stream>>>(part2, b, wx, ln_gamma, ln_beta, wh, wy);
        k_eta_part<8><<<nWh, 256, 0, stream>>>(wh, pred_eta, part);
        k_red    <<<dim3(4, NGRP), 256, 0, stream>>>(part, part2, cpg);
        k_eta_fin<<<4, 256, 0, stream>>>(part2, pred_eta_b, eta);
    } else {
        int nWh = 2 * (N / 32);  // 256
        k_combo1<32><<<nWh + N, 256, 0, stream>>>(x, w_in, hid, w, alpha, hebb, part, wx, nWh);
        k_red    <<<dim3(4, NGRP), 256, 0, stream>>>(part, part2, cpg);
        k_ln     <<<1, 1024, 0, stream>>>(part2, b, wx, ln_gamma, ln_beta, wh, wy);
        k_eta_part<32><<<nWh, 256, 0, stream>>>(wh, pred_eta, part);
        k_red    <<<dim3(4, NGRP), 256, 0, stream>>>(part, part2, cpg);
        k_eta_fin<<<4, 256, 0, stream>>>(part2, pred_eta_b, eta);
    }
    k_hebb<<<N, 256, 0, stream>>>(hebb, eta, hid, wh, lamda, hebb_out);
}

// Round 6
// 107.734 us; speedup vs baseline: 1.0770x; 1.0770x over previous
//
#include <hip/hip_runtime.h>
#include <hip/hip_bf16.h>
#include <math.h>

#define N 4096
#define NGRP 16
#define NF4 (N * (N / 4))      // float4 count per matrix = 4M

typedef float f32x4 __attribute__((ext_vector_type(4)));

__inline__ __device__ float waveReduceSum(float v) {
    #pragma unroll
    for (int o = 32; o > 0; o >>= 1) v += __shfl_down(v, o);
    return v;
}

#define LD4(p, o) (*reinterpret_cast<const float4*>((p) + (o)))

// Coherent-front sweep for wh partials.
// flat4 = k*G*256 + b*256 + t; i = flat4>>10 (block-uniform), j0 = (flat4 & 1023)*4 (fixed per thread).
// Each thread accumulates its fixed 4 columns over rows {k*(G/4) + (b>>2)}.
// part[p][j], p = b>>2, P = G/4 partials.
__global__ __launch_bounds__(256) void k_sweep_wh(const float* __restrict__ hid,
                                                  const float* __restrict__ w,
                                                  const float* __restrict__ alpha,
                                                  const float* __restrict__ hebb,
                                                  float* __restrict__ part,
                                                  int G, int iters) {
    int b = blockIdx.x, t = threadIdx.x;
    int p = b >> 2;
    int j0 = (((b & 3) << 8) | t) * 4;
    int P = G >> 2;
    float4 acc = make_float4(0.f, 0.f, 0.f, 0.f);
    size_t step = (size_t)G * 1024;          // elements advanced per iter
    size_t off = (size_t)(((b << 8) | t)) * 4;
    #pragma unroll 8
    for (int k = 0; k < iters; ++k, off += step) {
        float h = hid[k * P + p];
        float4 wv = LD4(w, off);
        float4 av = LD4(alpha, off);
        float4 hv = LD4(hebb, off);
        acc.x = fmaf(h, fmaf(av.x, hv.x, wv.x), acc.x);
        acc.y = fmaf(h, fmaf(av.y, hv.y, wv.y), acc.y);
        acc.z = fmaf(h, fmaf(av.z, hv.z, wv.z), acc.z);
        acc.w = fmaf(h, fmaf(av.w, hv.w, wv.w), acc.w);
    }
    *reinterpret_cast<float4*>(part + (size_t)p * N + j0) = acc;
}

// Same sweep, single matrix (pred_eta), multiplier wh[i].
__global__ __launch_bounds__(256) void k_sweep_eta(const float* __restrict__ wh,
                                                   const float* __restrict__ pe,
                                                   float* __restrict__ part,
                                                   int G, int iters) {
    int b = blockIdx.x, t = threadIdx.x;
    int p = b >> 2;
    int j0 = (((b & 3) << 8) | t) * 4;
    int P = G >> 2;
    float4 acc = make_float4(0.f, 0.f, 0.f, 0.f);
    size_t step = (size_t)G * 1024;
    size_t off = (size_t)(((b << 8) | t)) * 4;
    #pragma unroll 8
    for (int k = 0; k < iters; ++k, off += step) {
        float h = wh[k * P + p];
        float4 pv = LD4(pe, off);
        acc.x = fmaf(h, pv.x, acc.x);
        acc.y = fmaf(h, pv.y, acc.y);
        acc.z = fmaf(h, pv.z, acc.z);
        acc.w = fmaf(h, pv.w, acc.w);
    }
    *reinterpret_cast<float4*>(part + (size_t)p * N + j0) = acc;
}

// Coherent sweep for wx: w_in row-reduction. Per iter, block-uniform row i,
// block covers 1024 contiguous cols -> per-iter block reduction, one scalar
// to part_wx[(b&3)*N + i]. wx[j] folded later in k_ln.
__global__ __launch_bounds__(256) void k_sweep_wx(const float* __restrict__ x,
                                                  const float* __restrict__ w_in,
                                                  float* __restrict__ part_wx,
                                                  int G, int iters) {
    __shared__ float red[4];
    int b = blockIdx.x, t = threadIdx.x;
    int p = b >> 2;
    int P = G >> 2;
    int j0 = (((b & 3) << 8) | t) * 4;
    float4 xv = LD4(x, j0);
    size_t step = (size_t)G * 1024;
    size_t off = (size_t)(((b << 8) | t)) * 4;
    int wid = t >> 6, lane = t & 63;
    for (int k = 0; k < iters; ++k, off += step) {
        float4 wv = LD4(w_in, off);
        float d = wv.x * xv.x + wv.y * xv.y + wv.z * xv.z + wv.w * xv.w;
        d = waveReduceSum(d);
        if (lane == 0) red[wid] = d;
        __syncthreads();
        if (t == 0)
            part_wx[(size_t)(b & 3) * N + (k * P + p)] = red[0] + red[1] + red[2] + red[3];
        __syncthreads();
    }
}

// level-1 reduction: part2[g][j] = sum over cpg partials
__global__ __launch_bounds__(256) void k_red(const float* __restrict__ part,
                                             float* __restrict__ part2,
                                             int cpg) {
    int g  = blockIdx.y;
    int j0 = (blockIdx.x * 256 + threadIdx.x) * 4;
    const float4* p4 = reinterpret_cast<const float4*>(part);
    float4 s = make_float4(0.f, 0.f, 0.f, 0.f);
    #pragma unroll 8
    for (int c = 0; c < cpg; ++c) {
        float4 v = p4[((size_t)(g * cpg + c) * N + j0) >> 2];
        s.x += v.x; s.y += v.y; s.z += v.z; s.w += v.w;
    }
    *reinterpret_cast<float4*>(part2 + (size_t)g * N + j0) = s;
}

// finalize wh from part2 (+b), wx from part_wx (+relu), s = wx+wh, LN, relu -> wy
__global__ __launch_bounds__(1024) void k_ln(const float* __restrict__ part2,
                                             const float* __restrict__ part_wx,
                                             const float* __restrict__ b,
                                             const float* __restrict__ gamma,
                                             const float* __restrict__ beta,
                                             float* __restrict__ wh_out,
                                             float* __restrict__ wy_out) {
    __shared__ float red[16];
    __shared__ float bc[2];
    int tid = threadIdx.x;
    int wid = tid >> 6, lane = tid & 63;
    float sv[4];
    float lsum = 0.f;
    #pragma unroll
    for (int q = 0; q < 4; ++q) {
        int j = q * 1024 + tid;
        float acc = b[j];
        #pragma unroll
        for (int g = 0; g < NGRP; ++g) acc += part2[(size_t)g * N + j];
        wh_out[j] = acc;
        float wx = part_wx[j] + part_wx[N + j] + part_wx[2 * N + j] + part_wx[3 * N + j];
        float s = acc + fmaxf(wx, 0.f);
        sv[q] = s;
        lsum += s;
    }
    float wv = waveReduceSum(lsum);
    if (lane == 0) red[wid] = wv;
    __syncthreads();
    if (tid < 64) {
        float t = (tid < 16) ? red[tid] : 0.f;
        t = waveReduceSum(t);
        if (tid == 0) bc[0] = t * (1.f / N);
    }
    __syncthreads();
    float mean = bc[0];
    __syncthreads();
    float lsq = 0.f;
    #pragma unroll
    for (int q = 0; q < 4; ++q) { float d = sv[q] - mean; lsq += d * d; }
    wv = waveReduceSum(lsq);
    if (lane == 0) red[wid] = wv;
    __syncthreads();
    if (tid < 64) {
        float t = (tid < 16) ? red[tid] : 0.f;
        t = waveReduceSum(t);
        if (tid == 0) bc[1] = t * (1.f / N);
    }
    __syncthreads();
    float rstd = rsqrtf(bc[1] + 1e-5f);
    #pragma unroll
    for (int q = 0; q < 4; ++q) {
        int j = q * 1024 + tid;
        float ln = fmaf(gamma[j] * (sv[q] - mean), rstd, beta[j]);
        wy_out[j] = fmaxf(ln, 0.f);
    }
}

// eta[j] = sigmoid(pb[j] + sum_g part2[g][j])
__global__ __launch_bounds__(256) void k_eta_fin(const float* __restrict__ part2,
                                                 const float* __restrict__ pb,
                                                 float* __restrict__ eta) {
    int j0 = (blockIdx.x * 256 + threadIdx.x) * 4;
    float4 s = *reinterpret_cast<const float4*>(pb + j0);
    #pragma unroll
    for (int g = 0; g < NGRP; ++g) {
        float4 v = *reinterpret_cast<const float4*>(part2 + (size_t)g * N + j0);
        s.x += v.x; s.y += v.y; s.z += v.z; s.w += v.w;
    }
    float4 r;
    r.x = 1.f / (1.f + expf(-s.x));
    r.y = 1.f / (1.f + expf(-s.y));
    r.z = 1.f / (1.f + expf(-s.z));
    r.w = 1.f / (1.f + expf(-s.w));
    *reinterpret_cast<float4*>(eta + j0) = r;
}

// Coherent sweep hebb update: out = decay*hebb + (eta[i]*hid[i])*wh[j]
__global__ __launch_bounds__(256) void k_hebb(const float* __restrict__ hebb,
                                              const float* __restrict__ eta,
                                              const float* __restrict__ hid,
                                              const float* __restrict__ wh,
                                              const float* __restrict__ lamda,
                                              float* __restrict__ out,
                                              int G, int iters) {
    int b = blockIdx.x, t = threadIdx.x;
    int p = b >> 2;
    int P = G >> 2;
    int j0 = (((b & 3) << 8) | t) * 4;
    float decay = 1.f - lamda[0];
    float4 w4 = LD4(wh, j0);
    size_t step = (size_t)G * 1024;
    size_t off = (size_t)(((b << 8) | t)) * 4;
    #pragma unroll 4
    for (int k = 0; k < iters; ++k, off += step) {
        int i = k * P + p;
        float coef = eta[i] * hid[i];
        float4 h = LD4(hebb, off);
        f32x4 r;
        r.x = fmaf(decay, h.x, coef * w4.x);
        r.y = fmaf(decay, h.y, coef * w4.y);
        r.z = fmaf(decay, h.z, coef * w4.z);
        r.w = fmaf(decay, h.w, coef * w4.w);
        __builtin_nontemporal_store(r, reinterpret_cast<f32x4*>(out + off));
    }
}

extern "C" void kernel_launch(void* const* d_in, const int* in_sizes, int n_in,
                              void* d_out, int out_size, void* d_ws, size_t ws_size,
                              hipStream_t stream) {
    const float* x         = (const float*)d_in[0];
    const float* hid       = (const float*)d_in[1];
    const float* hebb      = (const float*)d_in[2];
    const float* w_in      = (const float*)d_in[3];
    const float* w         = (const float*)d_in[4];
    const float* alpha     = (const float*)d_in[5];
    const float* b         = (const float*)d_in[6];
    const float* lamda     = (const float*)d_in[7];
    const float* pred_eta  = (const float*)d_in[8];
    const float* pred_eta_b= (const float*)d_in[9];
    const float* ln_gamma  = (const float*)d_in[10];
    const float* ln_beta   = (const float*)d_in[11];

    float* wy       = (float*)d_out;
    float* hebb_out = (float*)d_out + N;

    // choose G by workspace: need (G/4)*N + NGRP*N + 4*N + 2*N floats
    int G = 2048;
    if ((ws_size / 4) < ((size_t)(G / 4) * N + (NGRP + 6) * N)) G = 512;
    int P = G / 4;
    int iters = NF4 / (G * 256);
    int cpg = P / NGRP;

    float* ws      = (float*)d_ws;
    float* part    = ws;                         // P*N
    float* part2   = part + (size_t)P * N;       // NGRP*N
    float* part_wx = part2 + (size_t)NGRP * N;   // 4*N
    float* wh      = part_wx + 4 * N;            // N
    float* eta     = wh + N;                     // N

    k_sweep_wx <<<G, 256, 0, stream>>>(x, w_in, part_wx, G, iters);
    k_sweep_wh <<<G, 256, 0, stream>>>(hid, w, alpha, hebb, part, G, iters);
    k_red      <<<dim3(4, NGRP), 256, 0, stream>>>(part, part2, cpg);
    k_ln       <<<1, 1024, 0, stream>>>(part2, part_wx, b, ln_gamma, ln_beta, wh, wy);
    k_sweep_eta<<<G, 256, 0, stream>>>(wh, pred_eta, part, G, iters);
    k_red      <<<dim3(4, NGRP), 256, 0, stream>>>(part, part2, cpg);
    k_eta_fin  <<<4, 256, 0, stream>>>(part2, pred_eta_b, eta);
    k_hebb     <<<G, 256, 0, stream>>>(hebb, eta, hid, wh, lamda, hebb_out, G, iters);
}

// Round 7
// 101.293 us; speedup vs baseline: 1.1455x; 1.0636x over previous
//
#include <hip/hip_runtime.h>
#include <hip/hip_bf16.h>
#include <math.h>

#define N 4096
#define NGRP 16
#define NF4 (N * (N / 4))      // float4 count per matrix = 4M

typedef float f32x4 __attribute__((ext_vector_type(4)));

__inline__ __device__ float waveReduceSum(float v) {
    #pragma unroll
    for (int o = 32; o > 0; o >>= 1) v += __shfl_down(v, o);
    return v;
}

#define LD4(p, o) (*reinterpret_cast<const float4*>((p) + (o)))

__inline__ __device__ f32x4 ntld4(const float* p) {
    return __builtin_nontemporal_load(reinterpret_cast<const f32x4*>(p));
}

// Coherent-front sweep for wh partials, compile-time full unroll.
// w/alpha: non-temporal (read once per replay, don't pollute L3).
// hebb: normal load (kept L3-resident for k_hebb reuse).
template<int ITERS>
__global__ __launch_bounds__(256) void k_sweep_wh_t(const float* __restrict__ hid,
                                                    const float* __restrict__ w,
                                                    const float* __restrict__ alpha,
                                                    const float* __restrict__ hebb,
                                                    float* __restrict__ part,
                                                    int G) {
    int b = blockIdx.x, t = threadIdx.x;
    int p = b >> 2;
    int j0 = (((b & 3) << 8) | t) * 4;
    int P = G >> 2;
    size_t step = (size_t)G * 1024;
    size_t off = (size_t)(((b << 8) | t)) * 4;

    f32x4 wv[ITERS], av[ITERS], bv[ITERS];
    float hv[ITERS];
    #pragma unroll
    for (int k = 0; k < ITERS; ++k) {
        size_t o = off + (size_t)k * step;
        wv[k] = ntld4(w + o);
        av[k] = ntld4(alpha + o);
        bv[k] = *reinterpret_cast<const f32x4*>(hebb + o);
    }
    #pragma unroll
    for (int k = 0; k < ITERS; ++k) hv[k] = hid[k * P + p];

    f32x4 acc = {0.f, 0.f, 0.f, 0.f};
    #pragma unroll
    for (int k = 0; k < ITERS; ++k) {
        float h = hv[k];
        acc.x = fmaf(h, fmaf(av[k].x, bv[k].x, wv[k].x), acc.x);
        acc.y = fmaf(h, fmaf(av[k].y, bv[k].y, wv[k].y), acc.y);
        acc.z = fmaf(h, fmaf(av[k].z, bv[k].z, wv[k].z), acc.z);
        acc.w = fmaf(h, fmaf(av[k].w, bv[k].w, wv[k].w), acc.w);
    }
    *reinterpret_cast<f32x4*>(part + (size_t)p * N + j0) = acc;
}

// dynamic fallback (small workspace path)
__global__ __launch_bounds__(256) void k_sweep_wh(const float* __restrict__ hid,
                                                  const float* __restrict__ w,
                                                  const float* __restrict__ alpha,
                                                  const float* __restrict__ hebb,
                                                  float* __restrict__ part,
                                                  int G, int iters) {
    int b = blockIdx.x, t = threadIdx.x;
    int p = b >> 2;
    int j0 = (((b & 3) << 8) | t) * 4;
    int P = G >> 2;
    float4 acc = make_float4(0.f, 0.f, 0.f, 0.f);
    size_t step = (size_t)G * 1024;
    size_t off = (size_t)(((b << 8) | t)) * 4;
    #pragma unroll 8
    for (int k = 0; k < iters; ++k, off += step) {
        float h = hid[k * P + p];
        float4 wv = LD4(w, off);
        float4 av = LD4(alpha, off);
        float4 hv = LD4(hebb, off);
        acc.x = fmaf(h, fmaf(av.x, hv.x, wv.x), acc.x);
        acc.y = fmaf(h, fmaf(av.y, hv.y, wv.y), acc.y);
        acc.z = fmaf(h, fmaf(av.z, hv.z, wv.z), acc.z);
        acc.w = fmaf(h, fmaf(av.w, hv.w, wv.w), acc.w);
    }
    *reinterpret_cast<float4*>(part + (size_t)p * N + j0) = acc;
}

// eta sweep: pred_eta stays normal (L3-resident steady state).
__global__ __launch_bounds__(256) void k_sweep_eta(const float* __restrict__ wh,
                                                   const float* __restrict__ pe,
                                                   float* __restrict__ part,
                                                   int G, int iters) {
    int b = blockIdx.x, t = threadIdx.x;
    int p = b >> 2;
    int j0 = (((b & 3) << 8) | t) * 4;
    int P = G >> 2;
    float4 acc = make_float4(0.f, 0.f, 0.f, 0.f);
    size_t step = (size_t)G * 1024;
    size_t off = (size_t)(((b << 8) | t)) * 4;
    #pragma unroll 8
    for (int k = 0; k < iters; ++k, off += step) {
        float h = wh[k * P + p];
        float4 pv = LD4(pe, off);
        acc.x = fmaf(h, pv.x, acc.x);
        acc.y = fmaf(h, pv.y, acc.y);
        acc.z = fmaf(h, pv.z, acc.z);
        acc.w = fmaf(h, pv.w, acc.w);
    }
    *reinterpret_cast<float4*>(part + (size_t)p * N + j0) = acc;
}

// wx sweep: w_in normal (L3-resident steady state).
__global__ __launch_bounds__(256) void k_sweep_wx(const float* __restrict__ x,
                                                  const float* __restrict__ w_in,
                                                  float* __restrict__ part_wx,
                                                  int G, int iters) {
    __shared__ float red[4];
    int b = blockIdx.x, t = threadIdx.x;
    int p = b >> 2;
    int P = G >> 2;
    int j0 = (((b & 3) << 8) | t) * 4;
    float4 xv = LD4(x, j0);
    size_t step = (size_t)G * 1024;
    size_t off = (size_t)(((b << 8) | t)) * 4;
    int wid = t >> 6, lane = t & 63;
    for (int k = 0; k < iters; ++k, off += step) {
        float4 wv = LD4(w_in, off);
        float d = wv.x * xv.x + wv.y * xv.y + wv.z * xv.z + wv.w * xv.w;
        d = waveReduceSum(d);
        if (lane == 0) red[wid] = d;
        __syncthreads();
        if (t == 0)
            part_wx[(size_t)(b & 3) * N + (k * P + p)] = red[0] + red[1] + red[2] + red[3];
        __syncthreads();
    }
}

// level-1 reduction: part2[g][j] = sum over cpg partials
__global__ __launch_bounds__(256) void k_red(const float* __restrict__ part,
                                             float* __restrict__ part2,
                                             int cpg) {
    int g  = blockIdx.y;
    int j0 = (blockIdx.x * 256 + threadIdx.x) * 4;
    const float4* p4 = reinterpret_cast<const float4*>(part);
    float4 s = make_float4(0.f, 0.f, 0.f, 0.f);
    #pragma unroll 8
    for (int c = 0; c < cpg; ++c) {
        float4 v = p4[((size_t)(g * cpg + c) * N + j0) >> 2];
        s.x += v.x; s.y += v.y; s.z += v.z; s.w += v.w;
    }
    *reinterpret_cast<float4*>(part2 + (size_t)g * N + j0) = s;
}

// finalize wh from part2 (+b), wx from part_wx (+relu), s = wx+wh, LN, relu -> wy
__global__ __launch_bounds__(1024) void k_ln(const float* __restrict__ part2,
                                             const float* __restrict__ part_wx,
                                             const float* __restrict__ b,
                                             const float* __restrict__ gamma,
                                             const float* __restrict__ beta,
                                             float* __restrict__ wh_out,
                                             float* __restrict__ wy_out) {
    __shared__ float red[16];
    __shared__ float bc[2];
    int tid = threadIdx.x;
    int wid = tid >> 6, lane = tid & 63;
    float sv[4];
    float lsum = 0.f;
    #pragma unroll
    for (int q = 0; q < 4; ++q) {
        int j = q * 1024 + tid;
        float acc = b[j];
        #pragma unroll
        for (int g = 0; g < NGRP; ++g) acc += part2[(size_t)g * N + j];
        wh_out[j] = acc;
        float wx = part_wx[j] + part_wx[N + j] + part_wx[2 * N + j] + part_wx[3 * N + j];
        float s = acc + fmaxf(wx, 0.f);
        sv[q] = s;
        lsum += s;
    }
    float wv = waveReduceSum(lsum);
    if (lane == 0) red[wid] = wv;
    __syncthreads();
    if (tid < 64) {
        float t = (tid < 16) ? red[tid] : 0.f;
        t = waveReduceSum(t);
        if (tid == 0) bc[0] = t * (1.f / N);
    }
    __syncthreads();
    float mean = bc[0];
    __syncthreads();
    float lsq = 0.f;
    #pragma unroll
    for (int q = 0; q < 4; ++q) { float d = sv[q] - mean; lsq += d * d; }
    wv = waveReduceSum(lsq);
    if (lane == 0) red[wid] = wv;
    __syncthreads();
    if (tid < 64) {
        float t = (tid < 16) ? red[tid] : 0.f;
        t = waveReduceSum(t);
        if (tid == 0) bc[1] = t * (1.f / N);
    }
    __syncthreads();
    float rstd = rsqrtf(bc[1] + 1e-5f);
    #pragma unroll
    for (int q = 0; q < 4; ++q) {
        int j = q * 1024 + tid;
        float ln = fmaf(gamma[j] * (sv[q] - mean), rstd, beta[j]);
        wy_out[j] = fmaxf(ln, 0.f);
    }
}

// eta[j] = sigmoid(pb[j] + sum_g part2[g][j])
__global__ __launch_bounds__(256) void k_eta_fin(const float* __restrict__ part2,
                                                 const float* __restrict__ pb,
                                                 float* __restrict__ eta) {
    int j0 = (blockIdx.x * 256 + threadIdx.x) * 4;
    float4 s = *reinterpret_cast<const float4*>(pb + j0);
    #pragma unroll
    for (int g = 0; g < NGRP; ++g) {
        float4 v = *reinterpret_cast<const float4*>(part2 + (size_t)g * N + j0);
        s.x += v.x; s.y += v.y; s.z += v.z; s.w += v.w;
    }
    float4 r;
    r.x = 1.f / (1.f + expf(-s.x));
    r.y = 1.f / (1.f + expf(-s.y));
    r.z = 1.f / (1.f + expf(-s.z));
    r.w = 1.f / (1.f + expf(-s.w));
    *reinterpret_cast<float4*>(eta + j0) = r;
}

// hebb sweep: hebb normal load (L3 hit from sweep_wh's allocation); out nt store
__global__ __launch_bounds__(256) void k_hebb(const float* __restrict__ hebb,
                                              const float* __restrict__ eta,
                                              const float* __restrict__ hid,
                                              const float* __restrict__ wh,
                                              const float* __restrict__ lamda,
                                              float* __restrict__ out,
                                              int G, int iters) {
    int b = blockIdx.x, t = threadIdx.x;
    int p = b >> 2;
    int P = G >> 2;
    int j0 = (((b & 3) << 8) | t) * 4;
    float decay = 1.f - lamda[0];
    float4 w4 = LD4(wh, j0);
    size_t step = (size_t)G * 1024;
    size_t off = (size_t)(((b << 8) | t)) * 4;
    #pragma unroll 4
    for (int k = 0; k < iters; ++k, off += step) {
        int i = k * P + p;
        float coef = eta[i] * hid[i];
        float4 h = LD4(hebb, off);
        f32x4 r;
        r.x = fmaf(decay, h.x, coef * w4.x);
        r.y = fmaf(decay, h.y, coef * w4.y);
        r.z = fmaf(decay, h.z, coef * w4.z);
        r.w = fmaf(decay, h.w, coef * w4.w);
        __builtin_nontemporal_store(r, reinterpret_cast<f32x4*>(out + off));
    }
}

extern "C" void kernel_launch(void* const* d_in, const int* in_sizes, int n_in,
                              void* d_out, int out_size, void* d_ws, size_t ws_size,
                              hipStream_t stream) {
    const float* x         = (const float*)d_in[0];
    const float* hid       = (const float*)d_in[1];
    const float* hebb      = (const float*)d_in[2];
    const float* w_in      = (const float*)d_in[3];
    const float* w         = (const float*)d_in[4];
    const float* alpha     = (const float*)d_in[5];
    const float* b         = (const float*)d_in[6];
    const float* lamda     = (const float*)d_in[7];
    const float* pred_eta  = (const float*)d_in[8];
    const float* pred_eta_b= (const float*)d_in[9];
    const float* ln_gamma  = (const float*)d_in[10];
    const float* ln_beta   = (const float*)d_in[11];

    float* wy       = (float*)d_out;
    float* hebb_out = (float*)d_out + N;

    int G = 2048;
    if ((ws_size / 4) < ((size_t)(G / 4) * N + (NGRP + 6) * N)) G = 512;
    int P = G / 4;
    int iters = NF4 / (G * 256);
    int cpg = P / NGRP;

    float* ws      = (float*)d_ws;
    float* part    = ws;                         // P*N
    float* part2   = part + (size_t)P * N;       // NGRP*N
    float* part_wx = part2 + (size_t)NGRP * N;   // 4*N
    float* wh      = part_wx + 4 * N;            // N
    float* eta     = wh + N;                     // N

    if (G == 2048) {
        k_sweep_wh_t<8><<<G, 256, 0, stream>>>(hid, w, alpha, hebb, part, G);
    } else {
        k_sweep_wh<<<G, 256, 0, stream>>>(hid, w, alpha, hebb, part, G, iters);
    }
    k_sweep_wx <<<G, 256, 0, stream>>>(x, w_in, part_wx, G, iters);
    k_red      <<<dim3(4, NGRP), 256, 0, stream>>>(part, part2, cpg);
    k_ln       <<<1, 1024, 0, stream>>>(part2, part_wx, b, ln_gamma, ln_beta, wh, wy);
    k_sweep_eta<<<G, 256, 0, stream>>>(wh, pred_eta, part, G, iters);
    k_red      <<<dim3(4, NGRP), 256, 0, stream>>>(part, part2, cpg);
    k_eta_fin  <<<4, 256, 0, stream>>>(part2, pred_eta_b, eta);
    k_hebb     <<<G, 256, 0, stream>>>(hebb, eta, hid, wh, lamda, hebb_out, G, iters);
}

// Round 8
// 98.029 us; speedup vs baseline: 1.1836x; 1.0333x over previous
//
#include <hip/hip_runtime.h>
#include <hip/hip_bf16.h>
#include <math.h>

#define N 4096
#define NGRP 16

typedef float f32x4 __attribute__((ext_vector_type(4)));

__inline__ __device__ float waveReduceSum(float v) {
    #pragma unroll
    for (int o = 32; o > 0; o >>= 1) v += __shfl_down(v, o);
    return v;
}

#define LD4(p, o) (*reinterpret_cast<const float4*>((p) + (o)))

__inline__ __device__ f32x4 ntld4(const float* p) {
    return __builtin_nontemporal_load(reinterpret_cast<const f32x4*>(p));
}

// Phase 1: blocks [0,G) = wh sweep (w/alpha nt, hebb cached); blocks [G, G+N) = wx rows.
template<int ITERS>
__global__ __launch_bounds__(256) void k_phase1(const float* __restrict__ x,
                                                const float* __restrict__ w_in,
                                                const float* __restrict__ hid,
                                                const float* __restrict__ w,
                                                const float* __restrict__ alpha,
                                                const float* __restrict__ hebb,
                                                float* __restrict__ part,
                                                float* __restrict__ wx_out,
                                                int G) {
    int t = threadIdx.x;
    if ((int)blockIdx.x < G) {
        int b = blockIdx.x;
        int p = b >> 2;
        int P = G >> 2;
        int j0 = (((b & 3) << 8) | t) * 4;
        size_t step = (size_t)G * 1024;
        size_t off = (size_t)(((b << 8) | t)) * 4;

        f32x4 wv[ITERS], av[ITERS], bv[ITERS];
        float hv[ITERS];
        #pragma unroll
        for (int k = 0; k < ITERS; ++k) {
            size_t o = off + (size_t)k * step;
            wv[k] = ntld4(w + o);
            av[k] = ntld4(alpha + o);
            bv[k] = *reinterpret_cast<const f32x4*>(hebb + o);
        }
        #pragma unroll
        for (int k = 0; k < ITERS; ++k) hv[k] = hid[k * P + p];

        f32x4 acc = {0.f, 0.f, 0.f, 0.f};
        #pragma unroll
        for (int k = 0; k < ITERS; ++k) {
            float h = hv[k];
            acc.x = fmaf(h, fmaf(av[k].x, bv[k].x, wv[k].x), acc.x);
            acc.y = fmaf(h, fmaf(av[k].y, bv[k].y, wv[k].y), acc.y);
            acc.z = fmaf(h, fmaf(av[k].z, bv[k].z, wv[k].z), acc.z);
            acc.w = fmaf(h, fmaf(av[k].w, bv[k].w, wv[k].w), acc.w);
        }
        *reinterpret_cast<f32x4*>(part + (size_t)p * N + j0) = acc;
    } else {
        int j = blockIdx.x - G;
        const float4* row = reinterpret_cast<const float4*>(w_in + (size_t)j * N);
        const float4* xv  = reinterpret_cast<const float4*>(x);
        float sum = 0.f;
        #pragma unroll
        for (int k = t; k < N / 4; k += 256) {
            float4 a = row[k], c = xv[k];
            sum += a.x * c.x + a.y * c.y + a.z * c.z + a.w * c.w;
        }
        sum = waveReduceSum(sum);
        __shared__ float wsum[4];
        int wid = t >> 6, lane = t & 63;
        if (lane == 0) wsum[wid] = sum;
        __syncthreads();
        if (t == 0)
            wx_out[j] = fmaxf(wsum[0] + wsum[1] + wsum[2] + wsum[3], 0.f);
    }
}

// level-1 reduction: part2[g][j] = sum over cpg partials
__global__ __launch_bounds__(256) void k_red(const float* __restrict__ part,
                                             float* __restrict__ part2,
                                             int cpg) {
    int g  = blockIdx.y;
    int j0 = (blockIdx.x * 256 + threadIdx.x) * 4;
    const float4* p4 = reinterpret_cast<const float4*>(part);
    float4 s = make_float4(0.f, 0.f, 0.f, 0.f);
    #pragma unroll 8
    for (int c = 0; c < cpg; ++c) {
        float4 v = p4[((size_t)(g * cpg + c) * N + j0) >> 2];
        s.x += v.x; s.y += v.y; s.z += v.z; s.w += v.w;
    }
    *reinterpret_cast<float4*>(part2 + (size_t)g * N + j0) = s;
}

// finalize wh from part2 (+b); s = wh + wx (wx already relu'd); LN; relu -> wy
__global__ __launch_bounds__(1024) void k_ln(const float* __restrict__ part2,
                                             const float* __restrict__ wx,
                                             const float* __restrict__ b,
                                             const float* __restrict__ gamma,
                                             const float* __restrict__ beta,
                                             float* __restrict__ wh_out,
                                             float* __restrict__ wy_out) {
    __shared__ float red[16];
    __shared__ float bc[2];
    int tid = threadIdx.x;
    int wid = tid >> 6, lane = tid & 63;
    float sv[4];
    float lsum = 0.f;
    #pragma unroll
    for (int q = 0; q < 4; ++q) {
        int j = q * 1024 + tid;
        float acc = b[j];
        #pragma unroll
        for (int g = 0; g < NGRP; ++g) acc += part2[(size_t)g * N + j];
        wh_out[j] = acc;
        float s = acc + wx[j];
        sv[q] = s;
        lsum += s;
    }
    float wv = waveReduceSum(lsum);
    if (lane == 0) red[wid] = wv;
    __syncthreads();
    if (tid < 64) {
        float t = (tid < 16) ? red[tid] : 0.f;
        t = waveReduceSum(t);
        if (tid == 0) bc[0] = t * (1.f / N);
    }
    __syncthreads();
    float mean = bc[0];
    __syncthreads();
    float lsq = 0.f;
    #pragma unroll
    for (int q = 0; q < 4; ++q) { float d = sv[q] - mean; lsq += d * d; }
    wv = waveReduceSum(lsq);
    if (lane == 0) red[wid] = wv;
    __syncthreads();
    if (tid < 64) {
        float t = (tid < 16) ? red[tid] : 0.f;
        t = waveReduceSum(t);
        if (tid == 0) bc[1] = t * (1.f / N);
    }
    __syncthreads();
    float rstd = rsqrtf(bc[1] + 1e-5f);
    #pragma unroll
    for (int q = 0; q < 4; ++q) {
        int j = q * 1024 + tid;
        float ln = fmaf(gamma[j] * (sv[q] - mean), rstd, beta[j]);
        wy_out[j] = fmaxf(ln, 0.f);
    }
}

// Fused eta + hebb update. 256 blocks x 1024 threads; block bk owns columns/rows
// [bk*16, bk*16+16).
// Phase A: eta[c] = sigmoid(sum_k wh[k]*pe[k][c] + pb[c]) for its 16 columns,
//   direct column-tile GEMV over L3-resident pred_eta.
// Phase B: stream 16 hebb rows: out[i][j] = (1-l)*hebb[i][j] + (eta[i]*hid[i])*wh[j].
__global__ __launch_bounds__(1024) void k_eta_hebb(const float* __restrict__ pe,
                                                   const float* __restrict__ pb,
                                                   const float* __restrict__ wh,
                                                   const float* __restrict__ hid,
                                                   const float* __restrict__ lamda,
                                                   const float* __restrict__ hebb,
                                                   float* __restrict__ out) {
    __shared__ float sm[64][17];
    __shared__ float coef_s[16];
    int t  = threadIdx.x;
    int i0 = blockIdx.x * 16;
    int cl = t & 15;          // column within tile
    int g  = t >> 4;          // rowgroup 0..63 (64 rows each)
    int c  = i0 + cl;

    float acc = 0.f;
    const float* perow = pe + (size_t)(g * 64) * N + c;
    const float* whp   = wh + g * 64;
    #pragma unroll 8
    for (int k = 0; k < 64; ++k)
        acc = fmaf(whp[k], perow[(size_t)k * N], acc);
    sm[g][cl] = acc;
    __syncthreads();
    #pragma unroll
    for (int off = 32; off >= 1; off >>= 1) {
        if (g < off) sm[g][cl] += sm[g + off][cl];
        __syncthreads();
    }
    if (t < 16) {
        int i = i0 + t;
        float eta = 1.f / (1.f + expf(-(sm[0][t] + pb[i])));
        coef_s[t] = eta * hid[i];
    }
    __syncthreads();

    float decay = 1.f - lamda[0];
    int j = (t & 1023) * 4;
    float4 w4 = LD4(wh, j);
    size_t base = (size_t)i0 * N + j;
    #pragma unroll 4
    for (int r = 0; r < 16; ++r) {
        float coef = coef_s[r];
        float4 h = LD4(hebb, base + (size_t)r * N);
        f32x4 o;
        o.x = fmaf(decay, h.x, coef * w4.x);
        o.y = fmaf(decay, h.y, coef * w4.y);
        o.z = fmaf(decay, h.z, coef * w4.z);
        o.w = fmaf(decay, h.w, coef * w4.w);
        __builtin_nontemporal_store(o, reinterpret_cast<f32x4*>(out + base + (size_t)r * N));
    }
}

extern "C" void kernel_launch(void* const* d_in, const int* in_sizes, int n_in,
                              void* d_out, int out_size, void* d_ws, size_t ws_size,
                              hipStream_t stream) {
    const float* x         = (const float*)d_in[0];
    const float* hid       = (const float*)d_in[1];
    const float* hebb      = (const float*)d_in[2];
    const float* w_in      = (const float*)d_in[3];
    const float* w         = (const float*)d_in[4];
    const float* alpha     = (const float*)d_in[5];
    const float* b         = (const float*)d_in[6];
    const float* lamda     = (const float*)d_in[7];
    const float* pred_eta  = (const float*)d_in[8];
    const float* pred_eta_b= (const float*)d_in[9];
    const float* ln_gamma  = (const float*)d_in[10];
    const float* ln_beta   = (const float*)d_in[11];

    float* wy       = (float*)d_out;
    float* hebb_out = (float*)d_out + N;

    // big path: G=2048 (P=512, part 8MB); fallback G=512 (P=128, part 2MB)
    int G = 2048;
    if ((ws_size / 4) < ((size_t)(G / 4) * N + (NGRP + 2) * (size_t)N)) G = 512;
    int P = G / 4;
    int cpg = P / NGRP;

    float* ws    = (float*)d_ws;
    float* part  = ws;                          // P*N
    float* part2 = part + (size_t)P * N;        // NGRP*N
    float* wx    = part2 + (size_t)NGRP * N;    // N
    float* wh    = wx + N;                      // N

    if (G == 2048) {
        k_phase1<8><<<G + N, 256, 0, stream>>>(x, w_in, hid, w, alpha, hebb, part, wx, G);
    } else {
        k_phase1<32><<<G + N, 256, 0, stream>>>(x, w_in, hid, w, alpha, hebb, part, wx, G);
    }
    k_red     <<<dim3(4, NGRP), 256, 0, stream>>>(part, part2, cpg);
    k_ln      <<<1, 1024, 0, stream>>>(part2, wx, b, ln_gamma, ln_beta, wh, wy);
    k_eta_hebb<<<256, 1024, 0, stream>>>(pred_eta, pred_eta_b, wh, hid, lamda, hebb, hebb_out);
}

// Round 9
// 97.665 us; speedup vs baseline: 1.1880x; 1.0037x over previous
//
#include <hip/hip_runtime.h>
#include <hip/hip_bf16.h>
#include <math.h>

#define N 4096
#define NGRP 16

typedef float f32x4 __attribute__((ext_vector_type(4)));

__inline__ __device__ float waveReduceSum(float v) {
    #pragma unroll
    for (int o = 32; o > 0; o >>= 1) v += __shfl_down(v, o);
    return v;
}

#define LD4(p, o) (*reinterpret_cast<const float4*>((p) + (o)))

__inline__ __device__ f32x4 ntld4(const float* p) {
    return __builtin_nontemporal_load(reinterpret_cast<const f32x4*>(p));
}

// Pure wh sweep (R7-verified 50us): w/alpha nt (stream, no L3 alloc), hebb cached.
template<int ITERS>
__global__ __launch_bounds__(256) void k_sweep_wh_t(const float* __restrict__ hid,
                                                    const float* __restrict__ w,
                                                    const float* __restrict__ alpha,
                                                    const float* __restrict__ hebb,
                                                    float* __restrict__ part,
                                                    int G) {
    int b = blockIdx.x, t = threadIdx.x;
    int p = b >> 2;
    int j0 = (((b & 3) << 8) | t) * 4;
    int P = G >> 2;
    size_t step = (size_t)G * 1024;
    size_t off = (size_t)(((b << 8) | t)) * 4;

    f32x4 wv[ITERS], av[ITERS], bv[ITERS];
    float hv[ITERS];
    #pragma unroll
    for (int k = 0; k < ITERS; ++k) {
        size_t o = off + (size_t)k * step;
        wv[k] = ntld4(w + o);
        av[k] = ntld4(alpha + o);
        bv[k] = *reinterpret_cast<const f32x4*>(hebb + o);
    }
    #pragma unroll
    for (int k = 0; k < ITERS; ++k) hv[k] = hid[k * P + p];

    f32x4 acc = {0.f, 0.f, 0.f, 0.f};
    #pragma unroll
    for (int k = 0; k < ITERS; ++k) {
        float h = hv[k];
        acc.x = fmaf(h, fmaf(av[k].x, bv[k].x, wv[k].x), acc.x);
        acc.y = fmaf(h, fmaf(av[k].y, bv[k].y, wv[k].y), acc.y);
        acc.z = fmaf(h, fmaf(av[k].z, bv[k].z, wv[k].z), acc.z);
        acc.w = fmaf(h, fmaf(av[k].w, bv[k].w, wv[k].w), acc.w);
    }
    *reinterpret_cast<f32x4*>(part + (size_t)p * N + j0) = acc;
}

// dynamic fallback (small workspace path)
__global__ __launch_bounds__(256) void k_sweep_wh(const float* __restrict__ hid,
                                                  const float* __restrict__ w,
                                                  const float* __restrict__ alpha,
                                                  const float* __restrict__ hebb,
                                                  float* __restrict__ part,
                                                  int G, int iters) {
    int b = blockIdx.x, t = threadIdx.x;
    int p = b >> 2;
    int j0 = (((b & 3) << 8) | t) * 4;
    int P = G >> 2;
    float4 acc = make_float4(0.f, 0.f, 0.f, 0.f);
    size_t step = (size_t)G * 1024;
    size_t off = (size_t)(((b << 8) | t)) * 4;
    #pragma unroll 8
    for (int k = 0; k < iters; ++k, off += step) {
        float h = hid[k * P + p];
        float4 wv = LD4(w, off);
        float4 av = LD4(alpha, off);
        float4 hv = LD4(hebb, off);
        acc.x = fmaf(h, fmaf(av.x, hv.x, wv.x), acc.x);
        acc.y = fmaf(h, fmaf(av.y, hv.y, wv.y), acc.y);
        acc.z = fmaf(h, fmaf(av.z, hv.z, wv.z), acc.z);
        acc.w = fmaf(h, fmaf(av.w, hv.w, wv.w), acc.w);
    }
    *reinterpret_cast<float4*>(part + (size_t)p * N + j0) = acc;
}

// Fused: blocks [0, nred) reduce partials (part2[g][j] = sum over cpg partials);
// blocks [nred, nred+N) compute wx row-dots from L3-resident w_in.
__global__ __launch_bounds__(256) void k_red_wx(const float* __restrict__ part,
                                                float* __restrict__ part2,
                                                int cpg,
                                                const float* __restrict__ x,
                                                const float* __restrict__ w_in,
                                                float* __restrict__ wx_out,
                                                int nred) {
    int t = threadIdx.x;
    if ((int)blockIdx.x < nred) {
        int g  = blockIdx.x >> 2;
        int xt = blockIdx.x & 3;
        int j0 = (xt * 256 + t) * 4;
        const float4* p4 = reinterpret_cast<const float4*>(part);
        float4 s = make_float4(0.f, 0.f, 0.f, 0.f);
        #pragma unroll 8
        for (int c = 0; c < cpg; ++c) {
            float4 v = p4[((size_t)(g * cpg + c) * N + j0) >> 2];
            s.x += v.x; s.y += v.y; s.z += v.z; s.w += v.w;
        }
        *reinterpret_cast<float4*>(part2 + (size_t)g * N + j0) = s;
    } else {
        int j = blockIdx.x - nred;
        const float4* row = reinterpret_cast<const float4*>(w_in + (size_t)j * N);
        const float4* xv  = reinterpret_cast<const float4*>(x);
        float sum = 0.f;
        #pragma unroll
        for (int k = t; k < N / 4; k += 256) {
            float4 a = row[k], c = xv[k];
            sum += a.x * c.x + a.y * c.y + a.z * c.z + a.w * c.w;
        }
        sum = waveReduceSum(sum);
        __shared__ float wsum[4];
        int wid = t >> 6, lane = t & 63;
        if (lane == 0) wsum[wid] = sum;
        __syncthreads();
        if (t == 0)
            wx_out[j] = fmaxf(wsum[0] + wsum[1] + wsum[2] + wsum[3], 0.f);
    }
}

// finalize wh from part2 (+b); s = wh + wx (wx already relu'd); LN; relu -> wy
__global__ __launch_bounds__(1024) void k_ln(const float* __restrict__ part2,
                                             const float* __restrict__ wx,
                                             const float* __restrict__ b,
                                             const float* __restrict__ gamma,
                                             const float* __restrict__ beta,
                                             float* __restrict__ wh_out,
                                             float* __restrict__ wy_out) {
    __shared__ float red[16];
    __shared__ float bc[2];
    int tid = threadIdx.x;
    int wid = tid >> 6, lane = tid & 63;
    float sv[4];
    float lsum = 0.f;
    #pragma unroll
    for (int q = 0; q < 4; ++q) {
        int j = q * 1024 + tid;
        float acc = b[j];
        #pragma unroll
        for (int g = 0; g < NGRP; ++g) acc += part2[(size_t)g * N + j];
        wh_out[j] = acc;
        float s = acc + wx[j];
        sv[q] = s;
        lsum += s;
    }
    float wv = waveReduceSum(lsum);
    if (lane == 0) red[wid] = wv;
    __syncthreads();
    if (tid < 64) {
        float t = (tid < 16) ? red[tid] : 0.f;
        t = waveReduceSum(t);
        if (tid == 0) bc[0] = t * (1.f / N);
    }
    __syncthreads();
    float mean = bc[0];
    __syncthreads();
    float lsq = 0.f;
    #pragma unroll
    for (int q = 0; q < 4; ++q) { float d = sv[q] - mean; lsq += d * d; }
    wv = waveReduceSum(lsq);
    if (lane == 0) red[wid] = wv;
    __syncthreads();
    if (tid < 64) {
        float t = (tid < 16) ? red[tid] : 0.f;
        t = waveReduceSum(t);
        if (tid == 0) bc[1] = t * (1.f / N);
    }
    __syncthreads();
    float rstd = rsqrtf(bc[1] + 1e-5f);
    #pragma unroll
    for (int q = 0; q < 4; ++q) {
        int j = q * 1024 + tid;
        float ln = fmaf(gamma[j] * (sv[q] - mean), rstd, beta[j]);
        wy_out[j] = fmaxf(ln, 0.f);
    }
}

// Fused eta + hebb update (R7-verified ~20us). 256 blocks x 1024 threads.
__global__ __launch_bounds__(1024) void k_eta_hebb(const float* __restrict__ pe,
                                                   const float* __restrict__ pb,
                                                   const float* __restrict__ wh,
                                                   const float* __restrict__ hid,
                                                   const float* __restrict__ lamda,
                                                   const float* __restrict__ hebb,
                                                   float* __restrict__ out) {
    __shared__ float sm[64][17];
    __shared__ float coef_s[16];
    int t  = threadIdx.x;
    int i0 = blockIdx.x * 16;
    int cl = t & 15;
    int g  = t >> 4;
    int c  = i0 + cl;

    float acc = 0.f;
    const float* perow = pe + (size_t)(g * 64) * N + c;
    const float* whp   = wh + g * 64;
    #pragma unroll 8
    for (int k = 0; k < 64; ++k)
        acc = fmaf(whp[k], perow[(size_t)k * N], acc);
    sm[g][cl] = acc;
    __syncthreads();
    #pragma unroll
    for (int off = 32; off >= 1; off >>= 1) {
        if (g < off) sm[g][cl] += sm[g + off][cl];
        __syncthreads();
    }
    if (t < 16) {
        int i = i0 + t;
        float eta = 1.f / (1.f + expf(-(sm[0][t] + pb[i])));
        coef_s[t] = eta * hid[i];
    }
    __syncthreads();

    float decay = 1.f - lamda[0];
    int j = (t & 1023) * 4;
    float4 w4 = LD4(wh, j);
    size_t base = (size_t)i0 * N + j;
    #pragma unroll 4
    for (int r = 0; r < 16; ++r) {
        float coef = coef_s[r];
        float4 h = LD4(hebb, base + (size_t)r * N);
        f32x4 o;
        o.x = fmaf(decay, h.x, coef * w4.x);
        o.y = fmaf(decay, h.y, coef * w4.y);
        o.z = fmaf(decay, h.z, coef * w4.z);
        o.w = fmaf(decay, h.w, coef * w4.w);
        __builtin_nontemporal_store(o, reinterpret_cast<f32x4*>(out + base + (size_t)r * N));
    }
}

extern "C" void kernel_launch(void* const* d_in, const int* in_sizes, int n_in,
                              void* d_out, int out_size, void* d_ws, size_t ws_size,
                              hipStream_t stream) {
    const float* x         = (const float*)d_in[0];
    const float* hid       = (const float*)d_in[1];
    const float* hebb      = (const float*)d_in[2];
    const float* w_in      = (const float*)d_in[3];
    const float* w         = (const float*)d_in[4];
    const float* alpha     = (const float*)d_in[5];
    const float* b         = (const float*)d_in[6];
    const float* lamda     = (const float*)d_in[7];
    const float* pred_eta  = (const float*)d_in[8];
    const float* pred_eta_b= (const float*)d_in[9];
    const float* ln_gamma  = (const float*)d_in[10];
    const float* ln_beta   = (const float*)d_in[11];

    float* wy       = (float*)d_out;
    float* hebb_out = (float*)d_out + N;

    int G = 2048;
    if ((ws_size / 4) < ((size_t)(G / 4) * N + (NGRP + 2) * (size_t)N)) G = 512;
    int P = G / 4;
    int cpg = P / NGRP;
    int nred = 4 * NGRP;  // 64 reduction blocks

    float* ws    = (float*)d_ws;
    float* part  = ws;                          // P*N
    float* part2 = part + (size_t)P * N;        // NGRP*N
    float* wx    = part2 + (size_t)NGRP * N;    // N
    float* wh    = wx + N;                      // N

    if (G == 2048) {
        k_sweep_wh_t<8><<<G, 256, 0, stream>>>(hid, w, alpha, hebb, part, G);
    } else {
        k_sweep_wh<<<G, 256, 0, stream>>>(hid, w, alpha, hebb, part, G, N * (N / 4) / (G * 256));
    }
    k_red_wx  <<<nred + N, 256, 0, stream>>>(part, part2, cpg, x, w_in, wx, nred);
    k_ln      <<<1, 1024, 0, stream>>>(part2, wx, b, ln_gamma, ln_beta, wh, wy);
    k_eta_hebb<<<256, 1024, 0, stream>>>(pred_eta, pred_eta_b, wh, hid, lamda, hebb, hebb_out);
}